// Round 7
// baseline (8044.238 us; speedup 1.0000x reference)
//
#include <hip/hip_runtime.h>

// ---------------------------------------------------------------------------
// MashDecoder forward. Round 6 (resubmit): head-batched attention (z=heads),
// single to_out GEMM (K=3328), split K/V proj, vectorized conv, DBC ld=64.
// B=4, NA=400, NQ=4096, D_HIDDEN=400, D_INNER=800, D_STATE=16, DT_RANK=25
// ---------------------------------------------------------------------------

#define EPI_NONE 0
#define EPI_SOFTPLUS 1
#define EPI_RES 2
#define EPI_GEGLU 3

typedef short bf16x8 __attribute__((ext_vector_type(8)));
typedef float f32x4 __attribute__((ext_vector_type(4)));

static __device__ __forceinline__ float silu_f(float x) {
  return x / (1.f + __expf(-x));
}
static __device__ __forceinline__ float softplus_f(float x) {
  return fmaxf(x, 0.f) + log1pf(__expf(-fabsf(x)));
}
static __device__ __forceinline__ float gelu_f(float x) {
  const float c = 0.7978845608028654f;  // sqrt(2/pi)
  return 0.5f * x * (1.f + tanhf(c * (x + 0.044715f * x * x * x)));
}
static __device__ __forceinline__ unsigned short f2bf(float f) {
  union { float f; unsigned int u; } v; v.f = f;
  unsigned int r = v.u + 0x7FFFu + ((v.u >> 16) & 1u);  // RNE
  return (unsigned short)(r >> 16);
}
static __device__ __forceinline__ float bf2f(unsigned short h) {
  union { unsigned int u; float f; } v; v.u = ((unsigned int)h) << 16;
  return v.f;
}

// ---------------------------------------------------------------------------
// Weight converts
// ---------------------------------------------------------------------------
// generic: src fp32 [L][R][C] -> dst bf16 [L][Rp][Cp], zero pad tail rows/cols
__global__ void cvt_w_kernel(const float* __restrict__ src, unsigned short* __restrict__ dst,
                             int Lr, int R, int C, int Rp, int Cp) {
  size_t i8 = ((size_t)blockIdx.x * 256 + threadIdx.x) * 8;
  size_t total = (size_t)Lr * Rp * Cp;
  if (i8 >= total) return;
  int cp = (int)(i8 % Cp);
  size_t rl = i8 / Cp;
  int r = (int)(rl % Rp);
  int l = (int)(rl / Rp);
  const float* s = src + ((size_t)l * R + r) * C + cp;
  bf16x8 o;
#pragma unroll
  for (int q = 0; q < 8; ++q) {
    float v = (r < R && (cp + q) < C) ? s[q] : 0.f;
    o[q] = (short)f2bf(v);
  }
  *reinterpret_cast<bf16x8*>(dst + i8) = o;
}

// per-head row pad: src [HB*400][400] -> dst [HB*416][416], zero pads
__global__ void cvt_headrow_k(const float* __restrict__ src, unsigned short* __restrict__ dst,
                              int HB) {
  size_t i8 = ((size_t)blockIdx.x * 256 + threadIdx.x) * 8;
  size_t total = (size_t)HB * 416 * 416;
  if (i8 >= total) return;
  int c = (int)(i8 % 416);
  int n = (int)(i8 / 416);
  int head = n / 416, r = n % 416;
  const float* s = src + ((size_t)(head * 400 + r)) * 400 + c;
  bf16x8 o;
#pragma unroll
  for (int q = 0; q < 8; ++q) {
    float v = (r < 400 && (c + q) < 400) ? s[q] : 0.f;
    o[q] = (short)f2bf(v);
  }
  *reinterpret_cast<bf16x8*>(dst + i8) = o;
}

// per-head col pad: src [400][HB*400] -> dst [512][HB*416], zero pads
__global__ void cvt_colhead_k(const float* __restrict__ src, unsigned short* __restrict__ dst,
                              int HB) {
  size_t i8 = ((size_t)blockIdx.x * 256 + threadIdx.x) * 8;
  size_t total = (size_t)512 * HB * 416;
  if (i8 >= total) return;
  int cp = (int)(i8 % ((size_t)HB * 416));
  int r = (int)(i8 / ((size_t)HB * 416));
  int head = cp / 416, cc = cp % 416;
  bf16x8 o;
#pragma unroll
  for (int q = 0; q < 8; ++q) {
    int c = cc + q;
    float v = (r < 400 && c < 400) ? src[(size_t)r * (HB * 400) + head * 400 + c] : 0.f;
    o[q] = (short)f2bf(v);
  }
  *reinterpret_cast<bf16x8*>(dst + i8) = o;
}

// ---------------------------------------------------------------------------
// bf16 MFMA GEMM, z-batched: C[z][M,N] = epi(A[z][M,K] @ W[z][N,K]^T + bias)
// ---------------------------------------------------------------------------
template <int EPI, int OUTBF>
__global__ __launch_bounds__(256) void gemm_bf16_k(
    const unsigned short* __restrict__ A, int lda, long long zsA,
    const unsigned short* __restrict__ W, int ldw, long long zsW,
    const float* __restrict__ bias,
    const float* __restrict__ aux, int ldaux,
    void* __restrict__ Cout, int ldc, long long zsC,
    int M, int N, int K) {
  __shared__ unsigned short As[128 * 32];
  __shared__ unsigned short Bs[128 * 32];
  const int tid = threadIdx.x;
  const int lane = tid & 63;
  const int wid = tid >> 6;
  const int wr = wid >> 1, wc = wid & 1;
  const int m0 = blockIdx.y * 128, n0 = blockIdx.x * 128;
  const long long z = blockIdx.z;
  A += z * zsA;
  W += z * zsW;

  f32x4 acc[4][4];
#pragma unroll
  for (int i = 0; i < 4; ++i)
#pragma unroll
    for (int j = 0; j < 4; ++j) acc[i][j] = (f32x4){0.f, 0.f, 0.f, 0.f};

  const int i0 = tid;
  const int i1 = tid + 256;
  const unsigned short* gA0 = A + (size_t)(m0 + (i0 >> 2)) * lda + ((i0 & 3) << 3);
  const unsigned short* gA1 = A + (size_t)(m0 + (i1 >> 2)) * lda + ((i1 & 3) << 3);
  const unsigned short* gB0 = W + (size_t)(n0 + (i0 >> 2)) * ldw + ((i0 & 3) << 3);
  const unsigned short* gB1 = W + (size_t)(n0 + (i1 >> 2)) * ldw + ((i1 & 3) << 3);
  unsigned short* lA0 = &As[i0 * 8];
  unsigned short* lA1 = &As[i1 * 8];
  unsigned short* lB0 = &Bs[i0 * 8];
  unsigned short* lB1 = &Bs[i1 * 8];

  const int fr = lane & 15, fq = lane >> 4;
  const int arow = wr * 64 + fr;
  const int brow = wc * 64 + fr;

  for (int k0 = 0; k0 < K; k0 += 32) {
    __builtin_amdgcn_global_load_lds(
        (const __attribute__((address_space(1))) unsigned int*)(gA0 + k0),
        (__attribute__((address_space(3))) unsigned int*)lA0, 16, 0, 0);
    __builtin_amdgcn_global_load_lds(
        (const __attribute__((address_space(1))) unsigned int*)(gA1 + k0),
        (__attribute__((address_space(3))) unsigned int*)lA1, 16, 0, 0);
    __builtin_amdgcn_global_load_lds(
        (const __attribute__((address_space(1))) unsigned int*)(gB0 + k0),
        (__attribute__((address_space(3))) unsigned int*)lB0, 16, 0, 0);
    __builtin_amdgcn_global_load_lds(
        (const __attribute__((address_space(1))) unsigned int*)(gB1 + k0),
        (__attribute__((address_space(3))) unsigned int*)lB1, 16, 0, 0);
    __syncthreads();
    bf16x8 av[4], bv[4];
#pragma unroll
    for (int mi = 0; mi < 4; ++mi)
      av[mi] = *reinterpret_cast<const bf16x8*>(&As[(arow + mi * 16) * 32 + fq * 8]);
#pragma unroll
    for (int ni = 0; ni < 4; ++ni)
      bv[ni] = *reinterpret_cast<const bf16x8*>(&Bs[(brow + ni * 16) * 32 + fq * 8]);
#pragma unroll
    for (int mi = 0; mi < 4; ++mi)
#pragma unroll
      for (int ni = 0; ni < 4; ++ni)
        acc[mi][ni] =
            __builtin_amdgcn_mfma_f32_16x16x32_bf16(av[mi], bv[ni], acc[mi][ni], 0, 0, 0);
    __syncthreads();
  }

  float* Cf = (float*)Cout + z * zsC;
  unsigned short* Cb = (unsigned short*)Cout + z * zsC;
  const float* auxp = aux ? aux + z * zsC : aux;
#pragma unroll
  for (int mi = 0; mi < 4; ++mi) {
#pragma unroll
    for (int r = 0; r < 4; ++r) {
      int m = m0 + wr * 64 + mi * 16 + fq * 4 + r;
      if (m >= M) continue;
#pragma unroll
      for (int ni = 0; ni < 4; ++ni) {
        int n = n0 + wc * 64 + ni * 16 + fr;
        if (n >= N) continue;
        float v = acc[mi][ni][r];
        if (bias) v += bias[n];
        if (EPI == EPI_GEGLU) v = auxp[(size_t)m * ldaux + n] * gelu_f(v);
        else if (EPI == EPI_RES) v += auxp[(size_t)m * ldaux + n];
        if (OUTBF) Cb[(size_t)m * ldc + n] = f2bf(v);
        else Cf[(size_t)m * ldc + n] = v;
      }
    }
  }
}

// ---------------------------------------------------------------------------
// fp32 GEMM (tiny shapes: anchor embed K=54, dt-proj K=25)
// ---------------------------------------------------------------------------
template <int BM, int BN, int BK, int TM, int TN, int EPI>
__global__ __launch_bounds__(256) void gemm_k(
    const float* __restrict__ A, int lda,
    const float* __restrict__ W, int ldw,
    const float* __restrict__ bias,
    float* __restrict__ C, int ldc,
    int M, int N, int K) {
  __shared__ float As[BK][BM];
  __shared__ float Bs[BK][BN];
  const int tid = threadIdx.x;
  const int tx = tid % (BN / TN);
  const int ty = tid / (BN / TN);
  const int m0 = blockIdx.y * BM;
  const int n0 = blockIdx.x * BN;

  float acc[TM][TN];
#pragma unroll
  for (int i = 0; i < TM; ++i)
#pragma unroll
    for (int j = 0; j < TN; ++j) acc[i][j] = 0.f;

  const int a_row = (tid * 4) / BK;
  const int a_col = (tid * 4) % BK;

  for (int k0 = 0; k0 < K; k0 += BK) {
    {
      int gm = m0 + a_row, gk = k0 + a_col;
      float4 v = make_float4(0.f, 0.f, 0.f, 0.f);
      if (gm < M) {
        if (gk + 3 < K) {
          v = *reinterpret_cast<const float4*>(A + (size_t)gm * lda + gk);
        } else {
          float tmp[4];
#pragma unroll
          for (int q = 0; q < 4; ++q)
            tmp[q] = (gk + q < K) ? A[(size_t)gm * lda + gk + q] : 0.f;
          v = make_float4(tmp[0], tmp[1], tmp[2], tmp[3]);
        }
      }
      As[a_col + 0][a_row] = v.x;
      As[a_col + 1][a_row] = v.y;
      As[a_col + 2][a_row] = v.z;
      As[a_col + 3][a_row] = v.w;
    }
    {
      int gn = n0 + a_row, gk = k0 + a_col;
      float4 v = make_float4(0.f, 0.f, 0.f, 0.f);
      if (gn < N) {
        if (gk + 3 < K) {
          v = *reinterpret_cast<const float4*>(W + (size_t)gn * ldw + gk);
        } else {
          float tmp[4];
#pragma unroll
          for (int q = 0; q < 4; ++q)
            tmp[q] = (gk + q < K) ? W[(size_t)gn * ldw + gk + q] : 0.f;
          v = make_float4(tmp[0], tmp[1], tmp[2], tmp[3]);
        }
      }
      Bs[a_col + 0][a_row] = v.x;
      Bs[a_col + 1][a_row] = v.y;
      Bs[a_col + 2][a_row] = v.z;
      Bs[a_col + 3][a_row] = v.w;
    }
    __syncthreads();
#pragma unroll
    for (int kk = 0; kk < BK; ++kk) {
      float a[TM], bb[TN];
#pragma unroll
      for (int i = 0; i < TM; i += 4)
        *reinterpret_cast<float4*>(&a[i]) =
            *reinterpret_cast<const float4*>(&As[kk][ty * TM + i]);
#pragma unroll
      for (int j = 0; j < TN; j += 4)
        *reinterpret_cast<float4*>(&bb[j]) =
            *reinterpret_cast<const float4*>(&Bs[kk][tx * TN + j]);
#pragma unroll
      for (int i = 0; i < TM; ++i)
#pragma unroll
        for (int j = 0; j < TN; ++j) acc[i][j] = fmaf(a[i], bb[j], acc[i][j]);
    }
    __syncthreads();
  }

#pragma unroll
  for (int i = 0; i < TM; ++i) {
    int m = m0 + ty * TM + i;
    if (m >= M) continue;
#pragma unroll
    for (int j = 0; j < TN; ++j) {
      int n = n0 + tx * TN + j;
      if (n >= N) continue;
      float v = acc[i][j];
      if (bias) v += bias[n];
      if (EPI == EPI_SOFTPLUS) v = softplus_f(v);
      C[(size_t)m * ldc + n] = v;
    }
  }
}

// ---------------------------------------------------------------------------
// Point embeds
// ---------------------------------------------------------------------------
__global__ void anchor_embed_kernel(const float* __restrict__ mash,
                                    float* __restrict__ aemb) {
  int row = blockIdx.x;
  int lane = threadIdx.x;
  if (lane >= 54) return;
  const float PI = 3.14159265358979323846f;
  float e;
  if (lane < 48) {
    int j = (lane < 24) ? lane : lane - 24;
    int d = j >> 2, f = j & 3;  // nf = 4
    float v = mash[row * 31 + d] * (PI * (float)(1 << f));
    e = (lane < 24) ? sinf(v) : cosf(v);
  } else {
    e = mash[row * 31 + (lane - 48)];
  }
  aemb[row * 54 + lane] = e;
}

__global__ void point_embed_q_kernel(const float* __restrict__ qry,
                                     unsigned short* __restrict__ qep) {
  int row = blockIdx.x;
  int lane = threadIdx.x;
  const float PI = 3.14159265358979323846f;
  float e = 0.f;
  if (lane < 48) {
    int j = (lane < 24) ? lane : lane - 24;
    int d = j >> 3, f = j & 7;  // nf = 8
    float v = qry[row * 3 + d] * (PI * (float)(1 << f));
    e = (lane < 24) ? sinf(v) : cosf(v);
  } else if (lane < 51) {
    e = qry[row * 3 + (lane - 48)];
  }
  qep[(size_t)row * 64 + lane] = f2bf(e);
}

__global__ void copy_tail_kernel(const float* __restrict__ mash,
                                 float* __restrict__ x) {
  int idx = blockIdx.x * 256 + threadIdx.x;
  if (idx >= 1600 * 25) return;
  int row = idx / 25, j = idx % 25;
  x[row * 400 + 375 + j] = mash[row * 31 + 6 + j];
}

// ---------------------------------------------------------------------------
// Norms -> bf16 padded [rows][416]
// ---------------------------------------------------------------------------
__global__ void rmsnorm_bf16_kernel(const float* __restrict__ x,
                                    const float* __restrict__ w,
                                    unsigned short* __restrict__ out) {
  int row = blockIdx.x;
  int lane = threadIdx.x;
  float ss = 0.f;
  float vals[7];
  int nv = 0;
  for (int c = lane; c < 400; c += 64) {
    float v = x[(size_t)row * 400 + c];
    vals[nv++] = v;
    ss += v * v;
  }
#pragma unroll
  for (int off = 1; off < 64; off <<= 1) ss += __shfl_xor(ss, off);
  float r = rsqrtf(ss * (1.f / 400.f) + 1e-5f);
  nv = 0;
  for (int c = lane; c < 416; c += 64) {
    unsigned short o = 0;
    if (c < 400) o = f2bf(vals[nv++] * r * w[c]);
    out[(size_t)row * 416 + c] = o;
  }
}

__global__ void layernorm_bf16_kernel(const float* __restrict__ x,
                                      const float* __restrict__ w,
                                      const float* __restrict__ b,
                                      unsigned short* __restrict__ out) {
  int row = blockIdx.x;
  int lane = threadIdx.x;
  float s = 0.f, s2 = 0.f;
  float vals[7];
  int nv = 0;
  for (int c = lane; c < 400; c += 64) {
    float v = x[(size_t)row * 400 + c];
    vals[nv++] = v;
    s += v;
    s2 += v * v;
  }
#pragma unroll
  for (int off = 1; off < 64; off <<= 1) {
    s += __shfl_xor(s, off);
    s2 += __shfl_xor(s2, off);
  }
  float mu = s * (1.f / 400.f);
  float var = s2 * (1.f / 400.f) - mu * mu;
  float r = rsqrtf(var + 1e-5f);
  nv = 0;
  for (int c = lane; c < 416; c += 64) {
    unsigned short o = 0;
    if (c < 400) o = f2bf((vals[nv++] - mu) * r * w[c] + b[c]);
    out[(size_t)row * 416 + c] = o;
  }
}

// ---------------------------------------------------------------------------
// Mamba pieces
// ---------------------------------------------------------------------------
// 4 channels/thread, float4 loads
__global__ void conv_silu_kernel(const float* __restrict__ uz,
                                 const float* __restrict__ cw,
                                 const float* __restrict__ cb,
                                 unsigned short* __restrict__ ucb,
                                 float* __restrict__ uc32) {
  int idx = (blockIdx.x * 256 + threadIdx.x) * 4;
  if (idx >= 1600 * 800) return;
  int c = idx % 800;
  int row = idx / 800;
  int l = row % 400;
  int b = row / 400;
  const float* ub = uz + (size_t)b * 400 * 1600 + c;
  float4 acc = *reinterpret_cast<const float4*>(cb + c);
  float wk[4][4];  // [channel i][tap k]
#pragma unroll
  for (int i = 0; i < 4; ++i) {
    float4 t = *reinterpret_cast<const float4*>(cw + (size_t)(c + i) * 4);
    wk[i][0] = t.x; wk[i][1] = t.y; wk[i][2] = t.z; wk[i][3] = t.w;
  }
#pragma unroll
  for (int k = 0; k < 4; ++k) {
    int ls = l - 3 + k;
    if (ls < 0) continue;
    float4 u = *reinterpret_cast<const float4*>(ub + (size_t)ls * 1600);
    acc.x = fmaf(u.x, wk[0][k], acc.x);
    acc.y = fmaf(u.y, wk[1][k], acc.y);
    acc.z = fmaf(u.z, wk[2][k], acc.z);
    acc.w = fmaf(u.w, wk[3][k], acc.w);
  }
  float4 v = make_float4(silu_f(acc.x), silu_f(acc.y), silu_f(acc.z), silu_f(acc.w));
  *reinterpret_cast<float4*>(uc32 + idx) = v;
  union { unsigned short s[4]; uint2 u; } o;
  o.s[0] = f2bf(v.x); o.s[1] = f2bf(v.y); o.s[2] = f2bf(v.z); o.s[3] = f2bf(v.w);
  *reinterpret_cast<uint2*>(ucb + idx) = o.u;
}

// 4 lanes per (b,d) channel; fused gate epilogue; 4-step pipelined loads.
// dbc rows padded to 64 floats.
__global__ void scan_kernel(const float* __restrict__ uc,
                            const float* __restrict__ dt,
                            const float* __restrict__ dbc,
                            const float* __restrict__ uz,
                            const float* __restrict__ A_log,
                            const float* __restrict__ Dp,
                            unsigned short* __restrict__ gb) {
  int t = blockIdx.x * 256 + threadIdx.x;
  if (t >= 12800) return;
  int g = t & 3;
  int bd = t >> 2;
  int b = bd / 800;
  int d = bd - b * 800;
  float A0 = -__expf(A_log[d * 16 + g * 4 + 0]);
  float A1 = -__expf(A_log[d * 16 + g * 4 + 1]);
  float A2 = -__expf(A_log[d * 16 + g * 4 + 2]);
  float A3 = -__expf(A_log[d * 16 + g * 4 + 3]);
  float Dpd = Dp[d];
  float h0 = 0.f, h1 = 0.f, h2 = 0.f, h3 = 0.f;
  const int off = 25 + g * 4;
  for (int l0 = 0; l0 < 400; l0 += 4) {
    float dtv[4], uv[4], zv[4], Bv[4][4], Cv[4][4];
#pragma unroll
    for (int q = 0; q < 4; ++q) {
      size_t base = (size_t)(b * 400 + l0 + q);
      dtv[q] = dt[base * 800 + d];
      uv[q] = uc[base * 800 + d];
      zv[q] = uz[base * 1600 + 800 + d];
      const float* bc = dbc + base * 64 + off;
#pragma unroll
      for (int s = 0; s < 4; ++s) {
        Bv[q][s] = bc[s];
        Cv[q][s] = bc[16 + s];
      }
    }
#pragma unroll
    for (int q = 0; q < 4; ++q) {
      float du = dtv[q] * uv[q];
      h0 = __expf(dtv[q] * A0) * h0 + du * Bv[q][0];
      h1 = __expf(dtv[q] * A1) * h1 + du * Bv[q][1];
      h2 = __expf(dtv[q] * A2) * h2 + du * Bv[q][2];
      h3 = __expf(dtv[q] * A3) * h3 + du * Bv[q][3];
      float yv = h0 * Cv[q][0] + h1 * Cv[q][1] + h2 * Cv[q][2] + h3 * Cv[q][3];
      yv += __shfl_xor(yv, 1);
      yv += __shfl_xor(yv, 2);
      if (g == 0) {
        size_t base = (size_t)(b * 400 + l0 + q);
        gb[base * 800 + d] = f2bf((yv + uv[q] * Dpd) * silu_f(zv[q]));
      }
    }
  }
}

// ---------------------------------------------------------------------------
// Softmax over 400 keys, in-place f32 S row -> bf16 P row (ld 416 f32)
// ---------------------------------------------------------------------------
__global__ void softmax_k(float* S) {
  int row = blockIdx.x * 4 + (threadIdx.x >> 6);
  int lane = threadIdx.x & 63;
  float* sr = S + (size_t)row * 416;
  float v[7];
  float m = -1e30f;
#pragma unroll
  for (int i = 0; i < 7; ++i) {
    int c = lane + i * 64;
    v[i] = (c < 400) ? sr[c] : -1e30f;
    m = fmaxf(m, v[i]);
  }
#pragma unroll
  for (int off = 1; off < 64; off <<= 1) m = fmaxf(m, __shfl_xor(m, off));
  float sum = 0.f;
#pragma unroll
  for (int i = 0; i < 7; ++i) {
    int c = lane + i * 64;
    float p = (c < 400) ? __expf(0.05f * (v[i] - m)) : 0.f;
    v[i] = p;
    sum += p;
  }
#pragma unroll
  for (int off = 1; off < 64; off <<= 1) sum += __shfl_xor(sum, off);
  float inv = 1.f / sum;
  unsigned short* pr = (unsigned short*)sr;
#pragma unroll
  for (int i = 0; i < 7; ++i) {
    int c = lane + i * 64;
    if (c < 400) pr[c] = f2bf(v[i] * inv);
    else if (c < 416) pr[c] = 0;
  }
}

// ---------------------------------------------------------------------------
// V transpose, all (b,h): VB [b*400+j][h*416+d] -> VT8 [(b*8+h)*512+d][416 j]
// grid (13 j-tiles, 8 d-tiles, 32 = b*8+h)
// ---------------------------------------------------------------------------
__global__ void vt_repack_k(const unsigned short* __restrict__ vb,
                            unsigned short* __restrict__ vt) {
  __shared__ unsigned short tbuf[32][66];
  int tid = threadIdx.x;
  int b = blockIdx.z >> 3, h = blockIdx.z & 7;
  int j0 = blockIdx.x * 32, d0 = blockIdx.y * 64;
  for (int idx = tid; idx < 32 * 64; idx += 256) {
    int j = idx >> 6, dd = idx & 63;
    unsigned short val = 0;
    if (j0 + j < 400 && d0 + dd < 400)
      val = vb[(size_t)(b * 400 + j0 + j) * 3328 + h * 416 + d0 + dd];
    tbuf[j][dd] = val;
  }
  __syncthreads();
  for (int idx = tid; idx < 64 * 32; idx += 256) {
    int dd = idx >> 5, j = idx & 31;
    vt[((size_t)(b * 8 + h) * 512 + d0 + dd) * 416 + j0 + j] = tbuf[j][dd];
  }
}

// ---------------------------------------------------------------------------
// head
// ---------------------------------------------------------------------------
__global__ void head_kernel(const float* __restrict__ lat,
                            const float* __restrict__ hw,
                            const float* __restrict__ hb,
                            float* __restrict__ out) {
  int row = blockIdx.x * 4 + (threadIdx.x >> 6);
  int lane = threadIdx.x & 63;
  float s = 0.f;
  for (int c = lane; c < 400; c += 64) s += lat[(size_t)row * 400 + c] * hw[c];
#pragma unroll
  for (int off = 1; off < 64; off <<= 1) s += __shfl_xor(s, off);
  if (lane == 0) out[row] = s + hb[0];
}

// ---------------------------------------------------------------------------
// host
// ---------------------------------------------------------------------------
static inline int cdiv(int a, int b) { return (a + b - 1) / b; }
static inline int cvtblocks(long long elems) { return (int)((elems / 8 + 255) / 256); }

extern "C" void kernel_launch(void* const* d_in, const int* in_sizes, int n_in,
                              void* d_out, int out_size, void* d_ws, size_t ws_size,
                              hipStream_t stream) {
  (void)in_sizes; (void)n_in; (void)out_size;

  const float* mash     = (const float*)d_in[0];
  const float* qry      = (const float*)d_in[1];
  const float* anchor_w = (const float*)d_in[2];
  const float* anchor_b = (const float*)d_in[3];
  const float* point_w  = (const float*)d_in[4];
  const float* point_b  = (const float*)d_in[5];
  const float* norm_w   = (const float*)d_in[6];
  const float* in_w     = (const float*)d_in[7];
  const float* conv_w   = (const float*)d_in[8];
  const float* conv_b   = (const float*)d_in[9];
  const float* xproj_w  = (const float*)d_in[10];
  const float* dt_w     = (const float*)d_in[11];
  const float* dt_b     = (const float*)d_in[12];
  const float* A_log    = (const float*)d_in[13];
  const float* Dp       = (const float*)d_in[14];
  const float* out_w    = (const float*)d_in[15];
  const float* ln_q_w   = (const float*)d_in[16];
  const float* ln_q_b   = (const float*)d_in[17];
  const float* ln_c_w   = (const float*)d_in[18];
  const float* ln_c_b   = (const float*)d_in[19];
  const float* to_q_w   = (const float*)d_in[20];
  const float* to_kv_w  = (const float*)d_in[21];
  const float* to_out_w = (const float*)d_in[22];
  const float* to_out_b = (const float*)d_in[23];
  const float* ff_ln_w  = (const float*)d_in[24];
  const float* ff_ln_b  = (const float*)d_in[25];
  const float* ff_w1    = (const float*)d_in[26];
  const float* ff_b1    = (const float*)d_in[27];
  const float* ff_w2    = (const float*)d_in[28];
  const float* ff_b2    = (const float*)d_in[29];
  const float* head_w   = (const float*)d_in[30];
  const float* head_b   = (const float*)d_in[31];

  // ---- workspace layout (float offsets) ----
  // R0: mamba weights; overlaid by attention scratch after mamba phase.
  const size_t WI   = 0;            // in_w bf16 [24][1664][416]  = 8,306,688
  const size_t WX   = 8306688;      // xproj bf16 [24][128][800]  = 1,228,800
  const size_t WO   = 9535488;      // out_w bf16 [24][512][800]  = 4,915,200
  //   R0 end = 14,450,688
  const size_t WK   = 14450688;     // K-proj bf16 [3328][416]    = 692,224
  const size_t WV   = 15142912;     // V-proj bf16 [3328][416]    = 692,224
  const size_t WP   = 15835136;     // point bf16 [512][64]       = 16,384
  const size_t WQ   = 15851520;     // to_q bf16 [3328][416]      = 692,224
  const size_t WTO  = 16543744;     // to_out bf16 [512][3328]    = 851,968
  const size_t WF1  = 17395712;     // ff_w1 bf16 [3264][416]     = 678,912
  const size_t WF2  = 18074624;     // ff_w2 bf16 [512][1600]     = 409,600
  const size_t XOFF = 18484224;     // X fp32 [1600][400]         = 640,000
  const size_t LATO = 19124224;     // LAT fp32 [16384][400]      = 6,553,600
  const size_t P    = 25677824;     // pool start
  // R0 overlays (attention):
  const size_t QEMB = 0;            // f32 [16384][400] (dead after qLN)
  const size_t VB   = 0;            // bf16 [1600][3328] (dead after repack)
  const size_t QEP  = 6553600;      // bf16 [16384][64]
  const size_t SOFF = 0;            // f32 [8][2048][416] = 6,815,744
  const size_t QH8  = 6815744;      // bf16 [8][4096][416] = 6,815,744 fl
  // pool: mamba scratch
  const size_t XNB  = P + 0;        // bf16 [1664][416]  = 346,112
  const size_t UZ   = P + 346112;   // f32 [1600][1600]  = 2,560,000
  const size_t UCB  = P + 2906112;  // bf16 [1664][800]  = 665,600
  const size_t UC32 = P + 3571712;  // f32 [1600][800]   = 1,280,000
  const size_t DTO  = P + 4851712;  // f32 [1600][800]   = 1,280,000
  const size_t DBC  = P + 6131712;  // f32 [1600][64]    = 102,400
  const size_t GB   = P + 6234112;  // bf16 [1664][800]  = 665,600
  const size_t AEMB = P + 6899712;  // f32 [1600][54]    = 86,400
  // pool: attention
  const size_t KB   = P + 0;        // bf16 [1600][3328] = 2,662,400
  const size_t QN   = P + 2662400;  // bf16 [16384][416] = 3,407,872
  const size_t VT8  = P + 6070272;  // bf16 [32][512][416] = 3,407,872
  const size_t OB   = P + 9478144;  // bf16 [4096][3328] = 6,815,744 (also CTX)
  // pool: FF
  const size_t LNL  = P + 0;        // bf16 [16384][416] = 3,407,872
  const size_t FFA  = P + 3407872;  // f32 [4096][1600]  = 6,553,600
  const size_t FFG  = P + 9961472;  // bf16 [4096][1600] = 3,276,800
  const size_t TOTAL = P + 16293888;  // 41,971,712 floats = 167.9 MB

  if (ws_size < TOTAL * sizeof(float)) return;

  float* ws = (float*)d_ws;
  float* X   = ws + XOFF;
  float* LAT = ws + LATO;
  unsigned short* pWI  = (unsigned short*)(ws + WI);
  unsigned short* pWX  = (unsigned short*)(ws + WX);
  unsigned short* pWO  = (unsigned short*)(ws + WO);
  unsigned short* pWK  = (unsigned short*)(ws + WK);
  unsigned short* pWV  = (unsigned short*)(ws + WV);
  unsigned short* pWP  = (unsigned short*)(ws + WP);
  unsigned short* pWQ  = (unsigned short*)(ws + WQ);
  unsigned short* pWTO = (unsigned short*)(ws + WTO);
  unsigned short* pWF1 = (unsigned short*)(ws + WF1);
  unsigned short* pWF2 = (unsigned short*)(ws + WF2);

  // ---- weight conversion ----
  cvt_w_kernel<<<cvtblocks(24LL*1664*416), 256, 0, stream>>>(in_w,   pWI, 24, 1600, 400, 1664, 416);
  cvt_w_kernel<<<cvtblocks(24LL*128*800),  256, 0, stream>>>(xproj_w,pWX, 24, 57,   800, 128,  800);
  cvt_w_kernel<<<cvtblocks(24LL*512*800),  256, 0, stream>>>(out_w,  pWO, 24, 400,  800, 512,  800);
  cvt_headrow_k<<<cvtblocks(8LL*416*416),  256, 0, stream>>>(to_kv_w, pWK, 8);
  cvt_headrow_k<<<cvtblocks(8LL*416*416),  256, 0, stream>>>(to_kv_w + 3200LL*400, pWV, 8);
  cvt_w_kernel<<<cvtblocks(512LL*64),      256, 0, stream>>>(point_w, pWP, 1, 400, 51, 512, 64);
  cvt_headrow_k<<<cvtblocks(8LL*416*416),  256, 0, stream>>>(to_q_w, pWQ, 8);
  cvt_colhead_k<<<cvtblocks(512LL*8*416),  256, 0, stream>>>(to_out_w, pWTO, 8);
  cvt_w_kernel<<<cvtblocks(3264LL*416),    256, 0, stream>>>(ff_w1, pWF1, 1, 3200, 400, 3264, 416);
  cvt_w_kernel<<<cvtblocks(512LL*1600),    256, 0, stream>>>(ff_w2, pWF2, 1, 400, 1600, 512, 1600);

  // ---- anchor embed -> X ----
  anchor_embed_kernel<<<1600, 64, 0, stream>>>(mash, ws + AEMB);
  gemm_k<64, 64, 16, 4, 4, EPI_NONE><<<dim3(6, 25), 256, 0, stream>>>(
      ws + AEMB, 54, anchor_w, 54, anchor_b, X, 400, 1600, 375, 54);
  copy_tail_kernel<<<cdiv(1600 * 25, 256), 256, 0, stream>>>(mash, X);

  // ---- 24 mamba blocks ----
  for (int L = 0; L < 24; ++L) {
    rmsnorm_bf16_kernel<<<1600, 64, 0, stream>>>(X, norm_w + (size_t)L * 400,
                                                 (unsigned short*)(ws + XNB));
    gemm_bf16_k<EPI_NONE, 0><<<dim3(13, 13), 256, 0, stream>>>(
        (unsigned short*)(ws + XNB), 416, 0, pWI + (size_t)L * 1664 * 416, 416, 0,
        nullptr, nullptr, 0, ws + UZ, 1600, 0, 1600, 1600, 416);
    conv_silu_kernel<<<1250, 256, 0, stream>>>(
        ws + UZ, conv_w + (size_t)L * 3200, conv_b + (size_t)L * 800,
        (unsigned short*)(ws + UCB), ws + UC32);
    gemm_bf16_k<EPI_NONE, 0><<<dim3(1, 13), 256, 0, stream>>>(
        (unsigned short*)(ws + UCB), 800, 0, pWX + (size_t)L * 128 * 800, 800, 0,
        nullptr, nullptr, 0, ws + DBC, 64, 0, 1600, 57, 800);
    gemm_k<64, 64, 16, 4, 4, EPI_SOFTPLUS><<<dim3(13, 25), 256, 0, stream>>>(
        ws + DBC, 64, dt_w + (size_t)L * 800 * 25, 25, dt_b + (size_t)L * 800,
        ws + DTO, 800, 1600, 800, 25);
    scan_kernel<<<50, 256, 0, stream>>>(ws + UC32, ws + DTO, ws + DBC, ws + UZ,
                                        A_log + (size_t)L * 12800,
                                        Dp + (size_t)L * 800,
                                        (unsigned short*)(ws + GB));
    gemm_bf16_k<EPI_RES, 0><<<dim3(4, 13), 256, 0, stream>>>(
        (unsigned short*)(ws + GB), 800, 0, pWO + (size_t)L * 512 * 800, 800, 0,
        nullptr, X, 400, X, 400, 0, 1600, 400, 800);
  }

  // ---- context LN -> K/V projections ----
  unsigned short* CTX = (unsigned short*)(ws + OB);  // transient in O slot
  layernorm_bf16_kernel<<<1600, 64, 0, stream>>>(X, ln_c_w, ln_c_b, CTX);
  gemm_bf16_k<EPI_NONE, 1><<<dim3(26, 13), 256, 0, stream>>>(
      CTX, 416, 0, pWK, 416, 0, nullptr, nullptr, 0,
      (unsigned short*)(ws + KB), 3328, 0, 1600, 3328, 416);
  gemm_bf16_k<EPI_NONE, 1><<<dim3(26, 13), 256, 0, stream>>>(
      CTX, 416, 0, pWV, 416, 0, nullptr, nullptr, 0,
      (unsigned short*)(ws + VB), 3328, 0, 1600, 3328, 416);
  vt_repack_k<<<dim3(13, 8, 32), 256, 0, stream>>>(
      (unsigned short*)(ws + VB), (unsigned short*)(ws + VT8));

  // ---- query embed -> point GEMM -> LN -> QN ----
  point_embed_q_kernel<<<16384, 64, 0, stream>>>(qry, (unsigned short*)(ws + QEP));
  gemm_bf16_k<EPI_NONE, 0><<<dim3(4, 128), 256, 0, stream>>>(
      (unsigned short*)(ws + QEP), 64, 0, pWP, 64, 0, point_b, nullptr, 0,
      ws + QEMB, 400, 0, 16384, 400, 64);
  layernorm_bf16_kernel<<<16384, 64, 0, stream>>>(ws + QEMB, ln_q_w, ln_q_b,
                                                  (unsigned short*)(ws + QN));

  // ---- attention: per batch, z = 8 heads ----
  for (int b = 0; b < 4; ++b) {
    // Qh[h] = QN_b @ Wq_h^T  -> QH8 [8][4096][416]
    gemm_bf16_k<EPI_NONE, 1><<<dim3(4, 32, 8), 256, 0, stream>>>(
        (unsigned short*)(ws + QN) + (size_t)b * 4096 * 416, 416, 0,
        pWQ, 416, 416LL * 416, nullptr, nullptr, 0,
        (unsigned short*)(ws + QH8), 416, 4096LL * 416, 4096, 416, 416);
    for (int half = 0; half < 2; ++half) {
      const unsigned short* Aq =
          (unsigned short*)(ws + QH8) + (size_t)half * 2048 * 416;
      // S[h] = Qh @ K_b^T (f32)
      gemm_bf16_k<EPI_NONE, 0><<<dim3(4, 16, 8), 256, 0, stream>>>(
          Aq, 416, 4096LL * 416,
          (unsigned short*)(ws + KB) + (size_t)b * 400 * 3328, 3328, 416LL,
          nullptr, nullptr, 0, ws + SOFF, 416, 2048LL * 416, 2048, 400, 416);
      // softmax all 8*2048 rows, in-place bf16 P
      softmax_k<<<4096, 256, 0, stream>>>(ws + SOFF);
      // O[., h*416..] = P @ V^T  (interleaved per-head columns)
      gemm_bf16_k<EPI_NONE, 1><<<dim3(4, 16, 8), 256, 0, stream>>>(
          (unsigned short*)(ws + SOFF), 832, 2048LL * 832,
          (unsigned short*)(ws + VT8) + (size_t)b * 8 * 512 * 416, 416, 512LL * 416,
          nullptr, nullptr, 0,
          (unsigned short*)(ws + OB) + (size_t)half * 2048 * 3328, 3328, 416LL,
          2048, 416, 416);
    }
    // LAT_b = O @ Wto^T + bias  (single GEMM over all heads, K=3328)
    gemm_bf16_k<EPI_NONE, 0><<<dim3(4, 32), 256, 0, stream>>>(
        (unsigned short*)(ws + OB), 3328, 0, pWTO, 3328, 0, to_out_b, nullptr, 0,
        LAT + (size_t)b * 4096 * 400, 400, 0, 4096, 400, 3328);
  }

  // ---- GEGLU FF (per batch) ----
  layernorm_bf16_kernel<<<16384, 64, 0, stream>>>(LAT, ff_ln_w, ff_ln_b,
                                                  (unsigned short*)(ws + LNL));
  for (int bb = 0; bb < 4; ++bb) {
    unsigned short* lnb = (unsigned short*)(ws + LNL) + (size_t)bb * 4096 * 416;
    float* latb = LAT + (size_t)bb * 4096 * 400;
    gemm_bf16_k<EPI_NONE, 0><<<dim3(13, 32), 256, 0, stream>>>(
        lnb, 416, 0, pWF1, 416, 0, ff_b1, nullptr, 0, ws + FFA, 1600, 0,
        4096, 1600, 416);
    gemm_bf16_k<EPI_GEGLU, 1><<<dim3(13, 32), 256, 0, stream>>>(
        lnb, 416, 0, pWF1 + (size_t)1600 * 416, 416, 0, ff_b1 + 1600,
        ws + FFA, 1600, (unsigned short*)(ws + FFG), 1600, 0, 4096, 1600, 416);
    gemm_bf16_k<EPI_RES, 0><<<dim3(4, 32), 256, 0, stream>>>(
        (unsigned short*)(ws + FFG), 1600, 0, pWF2, 1600, 0, ff_b2, latb, 400,
        latb, 400, 0, 4096, 400, 1600);
  }

  // ---- head ----
  head_kernel<<<4096, 256, 0, stream>>>(LAT, head_w, head_b, (float*)d_out);
}